// Round 2
// baseline (526.325 us; speedup 1.0000x reference)
//
#include <hip/hip_runtime.h>
#include <hip/hip_bf16.h>
#include <cstdint>
#include <cstddef>

// Problem constants (HybridMoE): T tokens, H hidden, I intermediate, E experts, top-2.
#define TT 2048
#define HH 2048
#define II 1408
#define EE 8
#define MAXROWS 5120   // sum of 128-padded per-expert counts <= 4096 + 8*127

typedef unsigned short u16;
typedef __attribute__((ext_vector_type(8))) __bf16 bf16x8;   // MFMA A/B operand (4 VGPRs)
typedef __attribute__((ext_vector_type(4))) float f32x4;     // MFMA C/D operand

typedef const __attribute__((address_space(1))) uint32_t* gas1_t;
typedef __attribute__((address_space(3))) uint32_t* las3_t;

// counted waitcnt (N = outstanding vector-mem ops allowed to remain)
#define VM_WAIT(N) asm volatile("s_waitcnt vmcnt(" #N ")" ::: "memory")
#define IR_FENCE() asm volatile("" ::: "memory")

// ---------- helpers ----------
__device__ __forceinline__ float bf2f(u16 b) {
    return __uint_as_float(((uint32_t)b) << 16);
}
__device__ __forceinline__ u16 f2bf(float x) {   // round-to-nearest-even
    uint32_t u = __float_as_uint(x);
    u += 0x7fffu + ((u >> 16) & 1u);
    return (u16)(u >> 16);
}

// ---------- dtype sniff: inputs f32 (flag=1) or bf16 (flag=0); also zeroes counts ----------
__global__ void k_sniff(const u16* __restrict__ raw, int* __restrict__ flag,
                        int* __restrict__ counts) {
    __shared__ int cnt;
    if (threadIdx.x < EE) counts[threadIdx.x] = 0;
    if (threadIdx.x == 0) cnt = 0;
    __syncthreads();
    int w = 0;
    for (int i = threadIdx.x; i < 4096; i += 256) {
        u16 x = raw[i];
        if (x & 0x7fff) {
            int ex = (x >> 7) & 0xff;
            if (ex == 0xff || ex < 100 || ex > 140) ++w;
        }
    }
    atomicAdd(&cnt, w);
    __syncthreads();
    if (threadIdx.x == 0) flag[0] = (cnt > 100) ? 1 : 0;
}

// ---------- routing: top-2 softmax -> per-expert token lists + per-token slot map ----------
__global__ void k_routing2(const void* __restrict__ logits, const int* __restrict__ flag,
                           int* __restrict__ counts, int* __restrict__ idx,
                           float* __restrict__ wt, int* __restrict__ slot) {
    int t = blockIdx.x * 256 + threadIdx.x;
    if (t >= TT) return;
    const int f = flag[0];
    float v[EE];
#pragma unroll
    for (int e = 0; e < EE; ++e)
        v[e] = f ? ((const float*)logits)[t * EE + e]
                 : bf2f(((const u16*)logits)[t * EE + e]);
    int i0 = 0; float v0 = v[0];
#pragma unroll
    for (int e = 1; e < EE; ++e) { if (v[e] > v0) { v0 = v[e]; i0 = e; } }
    int i1 = -1; float v1 = -3.4e38f;
#pragma unroll
    for (int e = 0; e < EE; ++e) { if (e != i0 && v[e] > v1) { v1 = v[e]; i1 = e; } }
    float r = __expf(v1 - v0);          // <= 1
    float s = 1.f / (1.f + r);
    int p0 = atomicAdd(&counts[i0], 1);
    idx[i0 * TT + p0] = t; wt[i0 * TT + p0] = s;
    slot[t * 2 + 0] = i0 * TT + p0;
    int p1 = atomicAdd(&counts[i1], 1);
    idx[i1 * TT + p1] = t; wt[i1 * TT + p1] = r * s;
    slot[t * 2 + 1] = i1 * TT + p1;
}

// ---------- offsets: meta[e]=row offset of expert e, meta[8+e]=padded count ----------
__global__ void k_offsets(const int* __restrict__ counts, int* __restrict__ meta) {
    if (threadIdx.x == 0 && blockIdx.x == 0) {
        int off = 0;
        for (int e = 0; e < EE; ++e) {
            int c = counts[e];
            int p = (c + 127) & ~127;
            meta[e] = off; meta[8 + e] = p;
            off += p;
        }
    }
}

// ---------- cast hidden_states to bf16 workspace copy ----------
__global__ void k_cast(const void* __restrict__ src, const int* __restrict__ flag,
                       u16* __restrict__ dst) {
    const int i0 = (blockIdx.x * 256 + threadIdx.x) * 8;
    if (flag[0]) {
        const float* s = (const float*)src;
#pragma unroll
        for (int j = 0; j < 8; ++j) dst[i0 + j] = f2bf(s[i0 + j]);
    } else {
        const u16* s = (const u16*)src;
        *(uint4*)&dst[i0] = *(const uint4*)&s[i0];
    }
}

// ---------- vectorized transpose per expert: src[R,C] (f32/bf16) -> dst[C,R] bf16 ----------
__global__ void k_transposeV(const void* __restrict__ src, const int* __restrict__ flag,
                             u16* __restrict__ dst, int R, int C) {
    __shared__ u16 t[64][68];
    const size_t eo = (size_t)blockIdx.z * (size_t)R * (size_t)C;
    const int r0 = blockIdx.y * 64, c0 = blockIdx.x * 64;
    const int tid = threadIdx.x;
    const int f = flag[0];
    {
        const int cg = tid & 15, rr = tid >> 4;    // load cols c0+cg*4..+3
#pragma unroll
        for (int p = 0; p < 4; ++p) {
            const int r = rr + p * 16;
            const size_t base = eo + (size_t)(r0 + r) * C + c0 + cg * 4;
            if (f) {
                const float4 v = *(const float4*)((const float*)src + base);
                t[r][cg * 4 + 0] = f2bf(v.x); t[r][cg * 4 + 1] = f2bf(v.y);
                t[r][cg * 4 + 2] = f2bf(v.z); t[r][cg * 4 + 3] = f2bf(v.w);
            } else {
                const ushort4 v = *(const ushort4*)((const u16*)src + base);
                t[r][cg * 4 + 0] = v.x; t[r][cg * 4 + 1] = v.y;
                t[r][cg * 4 + 2] = v.z; t[r][cg * 4 + 3] = v.w;
            }
        }
    }
    __syncthreads();
    {
        const int rg = tid & 15, cc = tid >> 4;    // store rows (cols of src)
#pragma unroll
        for (int p = 0; p < 4; ++p) {
            const int c = cc + p * 16;
            ushort4 o;
            o.x = t[rg * 4 + 0][c]; o.y = t[rg * 4 + 1][c];
            o.z = t[rg * 4 + 2][c]; o.w = t[rg * 4 + 3][c];
            *(ushort4*)(dst + eo + (size_t)(c0 + c) * R + r0 + rg * 4) = o;
        }
    }
}

// ================= GEMM1 sparse (dual), 512 threads / 8 waves =================
// 3-deep LDS pipeline, counted vmcnt (T3+T4): stage(t+2); vmcnt(6); barrier;
// compute(t); barrier.  Tile t is waited on TWO iterations after issue -> HBM/L3
// latency hidden.  Never vmcnt(0) in the main loop.
// Grid (e=8, m=16, n=11): linear%8==e pins each expert to one XCD; m fastest ->
// all m-blocks of an (e,n) B-panel run consecutively on that XCD (L2-resident
// 1MB panel; expert's gathered A rows ~2.2MB also L2-resident).
// XOR bank swizzle unchanged (round-1: conflicts 6.5e6 -> 0).

#define G1_COMPUTE(B) do { \
    __builtin_amdgcn_s_setprio(1); \
    bf16x8 af[4]; \
    _Pragma("unroll") \
    for (int mi = 0; mi < 4; ++mi) \
        af[mi] = *(const bf16x8*)&As[B][(wr + mi * 16 + ln) * 32 + qx]; \
    _Pragma("unroll") \
    for (int ni = 0; ni < 2; ++ni) { \
        bf16x8 bgf = *(const bf16x8*)&Bg[B][(wc + ni * 16 + ln) * 32 + qx]; \
        bf16x8 buf_ = *(const bf16x8*)&Bu[B][(wc + ni * 16 + ln) * 32 + qx]; \
        _Pragma("unroll") \
        for (int mi = 0; mi < 4; ++mi) { \
            accg[mi][ni] = __builtin_amdgcn_mfma_f32_16x16x32_bf16(af[mi], bgf, accg[mi][ni], 0, 0, 0); \
            accu[mi][ni] = __builtin_amdgcn_mfma_f32_16x16x32_bf16(af[mi], buf_, accu[mi][ni], 0, 0, 0); \
        } \
    } \
    __builtin_amdgcn_s_setprio(0); \
} while (0)

#define G1_STAGE(B, KB) do { \
    __builtin_amdgcn_global_load_lds((gas1_t)(pA + (KB)), (las3_t)(&As[B][dofs]), 16, 0, 0); \
    __builtin_amdgcn_global_load_lds((gas1_t)(pG + (KB)), (las3_t)(&Bg[B][dofs]), 16, 0, 0); \
    __builtin_amdgcn_global_load_lds((gas1_t)(pU + (KB)), (las3_t)(&Bu[B][dofs]), 16, 0, 0); \
} while (0)

__global__ __launch_bounds__(512, 4)
void k_gemm1s(const u16* __restrict__ hs_b,  // [T,H] bf16
              const u16* __restrict__ Wgt,   // [E,I,H] bf16
              const u16* __restrict__ Wut,   // [E,I,H] bf16
              const int* __restrict__ counts,
              const int* __restrict__ meta,
              const int* __restrict__ idx,
              const float* __restrict__ wt,
              u16* __restrict__ act_g) {     // [MAXROWS, I] bf16
    const int e = blockIdx.x;
    const int cnt = counts[e];
    const int pcnt = meta[8 + e];
    const int m0 = blockIdx.y * 128;
    if (m0 >= pcnt) return;
    const int n0 = blockIdx.z * 128;
    const int off = meta[e];
    const int tid = threadIdx.x;
    const int wave = tid >> 6, lane = tid & 63;
    const int ln = lane & 15, q = lane >> 4;
    const int wr = (wave >> 2) * 64;           // 2 m-rows of waves
    const int wc = (wave & 3) * 32;            // 4 n-cols of waves

    __shared__ __align__(16) u16 As[3][128 * 32];
    __shared__ __align__(16) u16 Bg[3][128 * 32];
    __shared__ __align__(16) u16 Bu[3][128 * 32];
    __shared__ int   tokS[128];
    __shared__ float wtS[128];

    if (tid < 128) {
        const int pos = m0 + tid;
        const bool v = pos < cnt;
        tokS[tid] = v ? idx[e * TT + pos] : 0;
        wtS[tid]  = v ? wt[e * TT + pos] : 0.f;
    }
    __syncthreads();   // vmcnt drained here -> pipeline starts from 0 outstanding

    // staging geometry: 512 threads x 16B = one 128x32 tile per issue; LDS dest linear,
    // source column XOR-swizzled so read chunk q^((row>>1)&3) returns global chunk q.
    const int srow = tid >> 2;                 // 0..127
    const int csw  = (((tid & 3) ^ ((srow >> 1) & 3))) * 8;
    const u16* pA = hs_b + (size_t)tokS[srow] * HH + csw;        // gathered token row
    const u16* pG = Wgt + ((size_t)e * II + n0 + srow) * HH + csw;
    const u16* pU = Wut + ((size_t)e * II + n0 + srow) * HH + csw;
    const int dofs = tid * 8;                  // == srow*32 + (tid&3)*8

    const int qx = (q ^ ((ln >> 1) & 3)) * 8;  // swizzled fragment-read chunk

    f32x4 accg[4][2], accu[4][2];
#pragma unroll
    for (int mi = 0; mi < 4; ++mi)
#pragma unroll
        for (int ni = 0; ni < 2; ++ni) { accg[mi][ni] = (f32x4)0.f; accu[mi][ni] = (f32x4)0.f; }

    // ---- 3-deep pipeline over 64 K-tiles ----
    G1_STAGE(0, 0);
    G1_STAGE(1, 32);
    int b0 = 0, b1 = 1, b2 = 2;
    for (int t = 0; t < 62; ++t) {
        G1_STAGE(b2, (t + 2) * 32);            // 9 outstanding / wave
        VM_WAIT(6);                            // tile t landed (t+1,t+2 in flight)
        __builtin_amdgcn_s_barrier();
        G1_COMPUTE(b0);
        IR_FENCE();
        __builtin_amdgcn_s_barrier();          // all waves done reading buf b0
        const int tb = b0; b0 = b1; b1 = b2; b2 = tb;
    }
    VM_WAIT(3);
    __builtin_amdgcn_s_barrier();
    G1_COMPUTE(b0);                            // tile 62
    VM_WAIT(0);
    __builtin_amdgcn_s_barrier();
    G1_COMPUTE(b1);                            // tile 63

    // epilogue: C/D layout col=lane&15, row=(lane>>4)*4+reg; pad rows have w=0 -> write 0
#pragma unroll
    for (int mi = 0; mi < 4; ++mi) {
#pragma unroll
        for (int r = 0; r < 4; ++r) {
            const int row = wr + mi * 16 + q * 4 + r;
            const float w = wtS[row];
#pragma unroll
            for (int ni = 0; ni < 2; ++ni) {
                const int i = n0 + wc + ni * 16 + ln;
                const float g = accg[mi][ni][r];
                const float u = accu[mi][ni][r];
                const float y = w * u * g / (1.f + __expf(-g));  // w * silu(g) * u
                act_g[(size_t)(off + m0 + row) * II + i] = f2bf(y);
            }
        }
    }
}

// ================= GEMM2 sparse: y_g[row] = act_g[row] @ Wd[e]; plain f32 stores =========
// Same 3-deep counted-vmcnt pipeline; 4 loads/stage -> steady wait = vmcnt(8).
#define G2_COMPUTE(B) do { \
    __builtin_amdgcn_s_setprio(1); \
    bf16x8 af[4]; \
    _Pragma("unroll") \
    for (int mi = 0; mi < 4; ++mi) \
        af[mi] = *(const bf16x8*)&As[B][(wr + mi * 16 + ln) * 32 + qx]; \
    _Pragma("unroll") \
    for (int ni = 0; ni < 4; ++ni) { \
        bf16x8 bf = *(const bf16x8*)&Bs[B][(wc + ni * 16 + ln) * 32 + qx]; \
        _Pragma("unroll") \
        for (int mi = 0; mi < 4; ++mi) \
            acc[mi][ni] = __builtin_amdgcn_mfma_f32_16x16x32_bf16(af[mi], bf, acc[mi][ni], 0, 0, 0); \
    } \
    __builtin_amdgcn_s_setprio(0); \
} while (0)

#define G2_STAGE(B, KB) do { \
    __builtin_amdgcn_global_load_lds((gas1_t)(pA0 + (KB)), (las3_t)(&As[B][dofs]), 16, 0, 0); \
    __builtin_amdgcn_global_load_lds((gas1_t)(pA1 + (KB)), (las3_t)(&As[B][2048 + dofs]), 16, 0, 0); \
    __builtin_amdgcn_global_load_lds((gas1_t)(pB0 + (KB)), (las3_t)(&Bs[B][dofs]), 16, 0, 0); \
    __builtin_amdgcn_global_load_lds((gas1_t)(pB1 + (KB)), (las3_t)(&Bs[B][2048 + dofs]), 16, 0, 0); \
} while (0)

__global__ __launch_bounds__(256, 3)
void k_gemm2s(const u16* __restrict__ act_g,  // [MAXROWS, I] bf16
              const u16* __restrict__ Wdt,    // [E,H,I] bf16
              const int* __restrict__ meta,
              float* __restrict__ y_g) {      // [MAXROWS, H] f32
    const int e = blockIdx.x;
    const int pcnt = meta[8 + e];
    const int m0 = blockIdx.y * 128;
    if (m0 >= pcnt) return;
    const int n0 = blockIdx.z * 128;
    const int off = meta[e];
    const int tid = threadIdx.x;
    const int wave = tid >> 6, lane = tid & 63;
    const int ln = lane & 15, q = lane >> 4;
    const int wr = (wave >> 1) * 64, wc = (wave & 1) * 64;

    __shared__ __align__(16) u16 As[3][128 * 32];
    __shared__ __align__(16) u16 Bs[3][128 * 32];

    // staging: 256 threads x 16B = half tile per issue; 2 issues per tile.
    const int srow = tid >> 2;                 // 0..63 (+64 for second half; swizzle identical)
    const int csw  = (((tid & 3) ^ ((srow >> 1) & 3))) * 8;
    const u16* bA = act_g + (size_t)(off + m0) * II;
    const u16* bB = Wdt + ((size_t)e * HH + n0) * II;
    const u16* pA0 = bA + (size_t)srow * II + csw;
    const u16* pA1 = bA + (size_t)(srow + 64) * II + csw;
    const u16* pB0 = bB + (size_t)srow * II + csw;
    const u16* pB1 = bB + (size_t)(srow + 64) * II + csw;
    const int dofs = tid * 8;

    const int qx = (q ^ ((ln >> 1) & 3)) * 8;

    f32x4 acc[4][4];
#pragma unroll
    for (int mi = 0; mi < 4; ++mi)
#pragma unroll
        for (int ni = 0; ni < 4; ++ni) acc[mi][ni] = (f32x4)0.f;

    // ---- 3-deep pipeline over 44 K-tiles ----
    G2_STAGE(0, 0);
    G2_STAGE(1, 32);
    int b0 = 0, b1 = 1, b2 = 2;
    for (int t = 0; t < 42; ++t) {
        G2_STAGE(b2, (t + 2) * 32);            // 12 outstanding / wave
        VM_WAIT(8);                            // tile t landed
        __builtin_amdgcn_s_barrier();
        G2_COMPUTE(b0);
        IR_FENCE();
        __builtin_amdgcn_s_barrier();
        const int tb = b0; b0 = b1; b1 = b2; b2 = tb;
    }
    VM_WAIT(4);
    __builtin_amdgcn_s_barrier();
    G2_COMPUTE(b0);                            // tile 42
    VM_WAIT(0);
    __builtin_amdgcn_s_barrier();
    G2_COMPUTE(b1);                            // tile 43

    // plain stores; padded rows (garbage) never read by k_combine
#pragma unroll
    for (int mi = 0; mi < 4; ++mi) {
#pragma unroll
        for (int r = 0; r < 4; ++r) {
            const int row = wr + mi * 16 + q * 4 + r;
            float* dst = y_g + (size_t)(off + m0 + row) * HH + n0 + wc;
#pragma unroll
            for (int ni = 0; ni < 4; ++ni)
                dst[ni * 16 + ln] = acc[mi][ni][r];
        }
    }
}

// ---------- combine: out[t] = y_g[slot0(t)] + y_g[slot1(t)] (weights folded in GEMM1) ----
__global__ void k_combine(const float* __restrict__ y_g, const int* __restrict__ slot,
                          const int* __restrict__ meta, const int* __restrict__ flag,
                          void* __restrict__ out) {
    const int gid = blockIdx.x * 256 + threadIdx.x;
    const int t = gid >> 9;                 // 512 threads per token row (H/4)
    const int h = (gid & 511) * 4;
    const int s0 = slot[t * 2 + 0], s1 = slot[t * 2 + 1];
    const int r0 = meta[s0 >> 11] + (s0 & 2047);   // TT == 2048
    const int r1 = meta[s1 >> 11] + (s1 & 2047);
    const float4 a = *(const float4*)&y_g[(size_t)r0 * HH + h];
    const float4 b = *(const float4*)&y_g[(size_t)r1 * HH + h];
    const float4 v = make_float4(a.x + b.x, a.y + b.y, a.z + b.z, a.w + b.w);
    if (flag[0]) {
        *(float4*)((float*)out + (size_t)t * HH + h) = v;
    } else {
        u16* o = (u16*)out + (size_t)t * HH + h;
        o[0] = f2bf(v.x); o[1] = f2bf(v.y); o[2] = f2bf(v.z); o[3] = f2bf(v.w);
    }
}

// ---------- launch ----------
extern "C" void kernel_launch(void* const* d_in, const int* in_sizes, int n_in,
                              void* d_out, int out_size, void* d_ws, size_t ws_size,
                              hipStream_t stream) {
    (void)in_sizes; (void)n_in; (void)out_size;
    const void* hs     = d_in[0];   // [T,H]
    const void* logits = d_in[1];   // [T,E]
    const void* Wg     = d_in[2];   // [E,H,I]
    const void* Wu     = d_in[3];   // [E,H,I]
    const void* Wd     = d_in[4];   // [E,I,H]

    char* ws = (char*)d_ws;
    size_t off = 0;
    int*   flag   = (int*)(ws + off);   off += 256;
    int*   counts = (int*)(ws + off);   off += 256;
    int*   meta   = (int*)(ws + off);   off += 256;
    int*   idx    = (int*)(ws + off);   off += (size_t)EE * TT * 4;       // 64 KB
    float* wt     = (float*)(ws + off); off += (size_t)EE * TT * 4;       // 64 KB
    int*   slot   = (int*)(ws + off);   off += (size_t)TT * 2 * 4;        // 16 KB
    u16*   hs_b   = (u16*)(ws + off);   off += (size_t)TT * HH * 2;       // 8 MB
    u16*   Wgt    = (u16*)(ws + off);   off += (size_t)EE * II * HH * 2;  // 46 MB [E,I,H]
    u16*   Wut    = (u16*)(ws + off);   off += (size_t)EE * II * HH * 2;  // 46 MB [E,I,H]
    u16*   Wdt    = (u16*)(ws + off);   off += (size_t)EE * HH * II * 2;  // 46 MB [E,H,I]
    u16*   act_g  = (u16*)(ws + off);   off += (size_t)MAXROWS * II * 2;  // 14.4 MB
    float* y_g    = (float*)(ws + off); off += (size_t)MAXROWS * HH * 4;  // 42 MB
    if (ws_size < off) return;

    k_sniff<<<dim3(1), dim3(256), 0, stream>>>((const u16*)hs, flag, counts);
    k_routing2<<<dim3(TT / 256), dim3(256), 0, stream>>>(logits, flag, counts, idx, wt, slot);
    k_offsets<<<dim3(1), dim3(64), 0, stream>>>(counts, meta);
    k_cast<<<dim3(TT * HH / (256 * 8)), dim3(256), 0, stream>>>(hs, flag, hs_b);
    // Wg [E,H,I] -> Wgt [E,I,H];  Wu likewise;  Wd [E,I,H] -> Wdt [E,H,I]
    k_transposeV<<<dim3(II / 64, HH / 64, EE), dim3(256), 0, stream>>>(Wg, flag, Wgt, HH, II);
    k_transposeV<<<dim3(II / 64, HH / 64, EE), dim3(256), 0, stream>>>(Wu, flag, Wut, HH, II);
    k_transposeV<<<dim3(HH / 64, II / 64, EE), dim3(256), 0, stream>>>(Wd, flag, Wdt, II, HH);
    // grid (e, m, n): linear%8==e -> expert pinned to XCD; m fastest -> B-panel L2 reuse
    k_gemm1s<<<dim3(EE, TT / 128, II / 128), dim3(512), 0, stream>>>(hs_b, Wgt, Wut, counts, meta, idx, wt, act_g);
    k_gemm2s<<<dim3(EE, TT / 128, HH / 128), dim3(256), 0, stream>>>(act_g, Wdt, meta, y_g);
    k_combine<<<dim3(TT * HH / (256 * 4)), dim3(256), 0, stream>>>(y_g, slot, meta, flag, d_out);
}

// Round 3
// 452.546 us; speedup vs baseline: 1.1630x; 1.1630x over previous
//
#include <hip/hip_runtime.h>
#include <hip/hip_bf16.h>
#include <cstdint>
#include <cstddef>

// Problem constants (HybridMoE): T tokens, H hidden, I intermediate, E experts, top-2.
#define TT 2048
#define HH 2048
#define II 1408
#define EE 8
#define MAXROWS 5120   // sum of 128-padded per-expert counts <= 4096 + 8*127

typedef unsigned short u16;
typedef __attribute__((ext_vector_type(8))) __bf16 bf16x8;   // MFMA A/B operand (4 VGPRs)
typedef __attribute__((ext_vector_type(4))) float f32x4;     // MFMA C/D operand

typedef const __attribute__((address_space(1))) uint32_t* gas1_t;
typedef __attribute__((address_space(3))) uint32_t* las3_t;

// counted waitcnt (N = outstanding vector-mem ops allowed to remain)
#define VM_WAIT(N) asm volatile("s_waitcnt vmcnt(" #N ")" ::: "memory")
#define IR_FENCE() asm volatile("" ::: "memory")

// ---------- helpers ----------
__device__ __forceinline__ float bf2f(u16 b) {
    return __uint_as_float(((uint32_t)b) << 16);
}
__device__ __forceinline__ u16 f2bf(float x) {   // round-to-nearest-even
    uint32_t u = __float_as_uint(x);
    u += 0x7fffu + ((u >> 16) & 1u);
    return (u16)(u >> 16);
}

// ---------- dtype sniff: inputs f32 (flag=1) or bf16 (flag=0); also zeroes counts ----------
__global__ void k_sniff(const u16* __restrict__ raw, int* __restrict__ flag,
                        int* __restrict__ counts) {
    __shared__ int cnt;
    if (threadIdx.x < EE) counts[threadIdx.x] = 0;
    if (threadIdx.x == 0) cnt = 0;
    __syncthreads();
    int w = 0;
    for (int i = threadIdx.x; i < 4096; i += 256) {
        u16 x = raw[i];
        if (x & 0x7fff) {
            int ex = (x >> 7) & 0xff;
            if (ex == 0xff || ex < 100 || ex > 140) ++w;
        }
    }
    atomicAdd(&cnt, w);
    __syncthreads();
    if (threadIdx.x == 0) flag[0] = (cnt > 100) ? 1 : 0;
}

// ---------- routing: top-2 softmax -> per-expert token lists + per-token slot map ----------
__global__ void k_routing2(const void* __restrict__ logits, const int* __restrict__ flag,
                           int* __restrict__ counts, int* __restrict__ idx,
                           float* __restrict__ wt, int* __restrict__ slot) {
    int t = blockIdx.x * 256 + threadIdx.x;
    if (t >= TT) return;
    const int f = flag[0];
    float v[EE];
#pragma unroll
    for (int e = 0; e < EE; ++e)
        v[e] = f ? ((const float*)logits)[t * EE + e]
                 : bf2f(((const u16*)logits)[t * EE + e]);
    int i0 = 0; float v0 = v[0];
#pragma unroll
    for (int e = 1; e < EE; ++e) { if (v[e] > v0) { v0 = v[e]; i0 = e; } }
    int i1 = -1; float v1 = -3.4e38f;
#pragma unroll
    for (int e = 0; e < EE; ++e) { if (e != i0 && v[e] > v1) { v1 = v[e]; i1 = e; } }
    float r = __expf(v1 - v0);          // <= 1
    float s = 1.f / (1.f + r);
    int p0 = atomicAdd(&counts[i0], 1);
    idx[i0 * TT + p0] = t; wt[i0 * TT + p0] = s;
    slot[t * 2 + 0] = i0 * TT + p0;
    int p1 = atomicAdd(&counts[i1], 1);
    idx[i1 * TT + p1] = t; wt[i1 * TT + p1] = r * s;
    slot[t * 2 + 1] = i1 * TT + p1;
}

// ---------- offsets: meta[e]=row offset of expert e, meta[8+e]=padded count ----------
__global__ void k_offsets(const int* __restrict__ counts, int* __restrict__ meta) {
    if (threadIdx.x == 0 && blockIdx.x == 0) {
        int off = 0;
        for (int e = 0; e < EE; ++e) {
            int c = counts[e];
            int p = (c + 127) & ~127;
            meta[e] = off; meta[8 + e] = p;
            off += p;
        }
    }
}

// ---------- cast hidden_states to bf16 workspace copy ----------
__global__ void k_cast(const void* __restrict__ src, const int* __restrict__ flag,
                       u16* __restrict__ dst) {
    const int i0 = (blockIdx.x * 256 + threadIdx.x) * 8;
    if (flag[0]) {
        const float* s = (const float*)src;
#pragma unroll
        for (int j = 0; j < 8; ++j) dst[i0 + j] = f2bf(s[i0 + j]);
    } else {
        const u16* s = (const u16*)src;
        *(uint4*)&dst[i0] = *(const uint4*)&s[i0];
    }
}

// ---------- vectorized transpose per expert: src[R,C] (f32/bf16) -> dst[C,R] bf16 ----------
__global__ void k_transposeV(const void* __restrict__ src, const int* __restrict__ flag,
                             u16* __restrict__ dst, int R, int C) {
    __shared__ u16 t[64][68];
    const size_t eo = (size_t)blockIdx.z * (size_t)R * (size_t)C;
    const int r0 = blockIdx.y * 64, c0 = blockIdx.x * 64;
    const int tid = threadIdx.x;
    const int f = flag[0];
    {
        const int cg = tid & 15, rr = tid >> 4;    // load cols c0+cg*4..+3
#pragma unroll
        for (int p = 0; p < 4; ++p) {
            const int r = rr + p * 16;
            const size_t base = eo + (size_t)(r0 + r) * C + c0 + cg * 4;
            if (f) {
                const float4 v = *(const float4*)((const float*)src + base);
                t[r][cg * 4 + 0] = f2bf(v.x); t[r][cg * 4 + 1] = f2bf(v.y);
                t[r][cg * 4 + 2] = f2bf(v.z); t[r][cg * 4 + 3] = f2bf(v.w);
            } else {
                const ushort4 v = *(const ushort4*)((const u16*)src + base);
                t[r][cg * 4 + 0] = v.x; t[r][cg * 4 + 1] = v.y;
                t[r][cg * 4 + 2] = v.z; t[r][cg * 4 + 3] = v.w;
            }
        }
    }
    __syncthreads();
    {
        const int rg = tid & 15, cc = tid >> 4;    // store rows (cols of src)
#pragma unroll
        for (int p = 0; p < 4; ++p) {
            const int c = cc + p * 16;
            ushort4 o;
            o.x = t[rg * 4 + 0][c]; o.y = t[rg * 4 + 1][c];
            o.z = t[rg * 4 + 2][c]; o.w = t[rg * 4 + 3][c];
            *(ushort4*)(dst + eo + (size_t)(c0 + c) * R + r0 + rg * 4) = o;
        }
    }
}

// ================= GEMM1 sparse (dual), 512 threads / 8 waves =================
// 2-buffer counted-vmcnt pipeline: stage(t+1); vmcnt(3); barrier; compute(t); barrier.
// The vmcnt(3) waits for tile t (issued ONE ITERATION earlier) -> latency partially
// hidden by the previous compute, at zero extra LDS (50KB -> 3 blocks/CU).
// Grid (e=8, n=11, m=16), m fastest: linear%8==e pins expert to XCD; consecutive
// blocks share the (e,n) B-panel (round-0 best: 85us, FETCH 53MB).
// XOR bank swizzle (round-1: conflicts 6.5e6 -> 0).

#define G1_COMPUTE(B) do { \
    __builtin_amdgcn_s_setprio(1); \
    bf16x8 af[4]; \
    _Pragma("unroll") \
    for (int mi = 0; mi < 4; ++mi) \
        af[mi] = *(const bf16x8*)&As[B][(wr + mi * 16 + ln) * 32 + qx]; \
    _Pragma("unroll") \
    for (int ni = 0; ni < 2; ++ni) { \
        bf16x8 bgf = *(const bf16x8*)&Bg[B][(wc + ni * 16 + ln) * 32 + qx]; \
        bf16x8 buf_ = *(const bf16x8*)&Bu[B][(wc + ni * 16 + ln) * 32 + qx]; \
        _Pragma("unroll") \
        for (int mi = 0; mi < 4; ++mi) { \
            accg[mi][ni] = __builtin_amdgcn_mfma_f32_16x16x32_bf16(af[mi], bgf, accg[mi][ni], 0, 0, 0); \
            accu[mi][ni] = __builtin_amdgcn_mfma_f32_16x16x32_bf16(af[mi], buf_, accu[mi][ni], 0, 0, 0); \
        } \
    } \
    __builtin_amdgcn_s_setprio(0); \
} while (0)

#define G1_STAGE(B, KB) do { \
    __builtin_amdgcn_global_load_lds((gas1_t)(pA + (KB)), (las3_t)(&As[B][dofs]), 16, 0, 0); \
    __builtin_amdgcn_global_load_lds((gas1_t)(pG + (KB)), (las3_t)(&Bg[B][dofs]), 16, 0, 0); \
    __builtin_amdgcn_global_load_lds((gas1_t)(pU + (KB)), (las3_t)(&Bu[B][dofs]), 16, 0, 0); \
} while (0)

__global__ __launch_bounds__(512, 4)
void k_gemm1s(const u16* __restrict__ hs_b,  // [T,H] bf16
              const u16* __restrict__ Wgt,   // [E,I,H] bf16
              const u16* __restrict__ Wut,   // [E,I,H] bf16
              const int* __restrict__ counts,
              const int* __restrict__ meta,
              const int* __restrict__ idx,
              const float* __restrict__ wt,
              u16* __restrict__ act_g) {     // [MAXROWS, I] bf16
    const int e = blockIdx.x;
    const int cnt = counts[e];
    const int pcnt = meta[8 + e];
    const int m0 = blockIdx.z * 128;
    if (m0 >= pcnt) return;
    const int n0 = blockIdx.y * 128;
    const int off = meta[e];
    const int tid = threadIdx.x;
    const int wave = tid >> 6, lane = tid & 63;
    const int ln = lane & 15, q = lane >> 4;
    const int wr = (wave >> 2) * 64;           // 2 m-rows of waves
    const int wc = (wave & 3) * 32;            // 4 n-cols of waves

    __shared__ __align__(16) u16 As[2][128 * 32];
    __shared__ __align__(16) u16 Bg[2][128 * 32];
    __shared__ __align__(16) u16 Bu[2][128 * 32];
    __shared__ int   tokS[128];
    __shared__ float wtS[128];

    if (tid < 128) {
        const int pos = m0 + tid;
        const bool v = pos < cnt;
        tokS[tid] = v ? idx[e * TT + pos] : 0;
        wtS[tid]  = v ? wt[e * TT + pos] : 0.f;
    }
    __syncthreads();   // tokS visible; vmcnt drained -> pipeline starts at 0 outstanding

    // staging geometry: 512 threads x 16B = one 128x32 tile per issue; LDS dest linear,
    // source column XOR-swizzled so read chunk q^((row>>1)&3) returns global chunk q.
    const int srow = tid >> 2;                 // 0..127
    const int csw  = (((tid & 3) ^ ((srow >> 1) & 3))) * 8;
    const u16* pA = hs_b + (size_t)tokS[srow] * HH + csw;        // gathered token row
    const u16* pG = Wgt + ((size_t)e * II + n0 + srow) * HH + csw;
    const u16* pU = Wut + ((size_t)e * II + n0 + srow) * HH + csw;
    const int dofs = tid * 8;                  // == srow*32 + (tid&3)*8

    const int qx = (q ^ ((ln >> 1) & 3)) * 8;  // swizzled fragment-read chunk

    f32x4 accg[4][2], accu[4][2];
#pragma unroll
    for (int mi = 0; mi < 4; ++mi)
#pragma unroll
        for (int ni = 0; ni < 2; ++ni) { accg[mi][ni] = (f32x4)0.f; accu[mi][ni] = (f32x4)0.f; }

    // ---- 2-buffer counted-vmcnt pipeline over 64 K-tiles ----
    G1_STAGE(0, 0);
    int cur = 0;
    for (int t = 0; t < 63; ++t) {
        G1_STAGE(cur ^ 1, (t + 1) * 32);       // 6 outstanding / wave
        VM_WAIT(3);                            // tile t (issued last iter) landed
        __builtin_amdgcn_s_barrier();          // all waves' tile-t parts landed
        G1_COMPUTE(cur);
        IR_FENCE();
        __builtin_amdgcn_s_barrier();          // all waves done reading buf cur
        cur ^= 1;
    }
    VM_WAIT(0);
    __builtin_amdgcn_s_barrier();
    G1_COMPUTE(cur);                           // tile 63

    // epilogue: C/D layout col=lane&15, row=(lane>>4)*4+reg; pad rows have w=0 -> write 0
#pragma unroll
    for (int mi = 0; mi < 4; ++mi) {
#pragma unroll
        for (int r = 0; r < 4; ++r) {
            const int row = wr + mi * 16 + q * 4 + r;
            const float w = wtS[row];
#pragma unroll
            for (int ni = 0; ni < 2; ++ni) {
                const int i = n0 + wc + ni * 16 + ln;
                const float g = accg[mi][ni][r];
                const float u = accu[mi][ni][r];
                const float y = w * u * g / (1.f + __expf(-g));  // w * silu(g) * u
                act_g[(size_t)(off + m0 + row) * II + i] = f2bf(y);
            }
        }
    }
}

// ================= GEMM2 sparse: y_g[row] = act_g[row] @ Wd[e]; plain f32 stores =========
// Same 2-buffer counted-vmcnt pipeline; 4 loads/stage -> in-loop wait = vmcnt(4).
// LDS 32KB -> 4 blocks/CU (vs 2 before).
#define G2_COMPUTE(B) do { \
    __builtin_amdgcn_s_setprio(1); \
    bf16x8 af[4]; \
    _Pragma("unroll") \
    for (int mi = 0; mi < 4; ++mi) \
        af[mi] = *(const bf16x8*)&As[B][(wr + mi * 16 + ln) * 32 + qx]; \
    _Pragma("unroll") \
    for (int ni = 0; ni < 4; ++ni) { \
        bf16x8 bf = *(const bf16x8*)&Bs[B][(wc + ni * 16 + ln) * 32 + qx]; \
        _Pragma("unroll") \
        for (int mi = 0; mi < 4; ++mi) \
            acc[mi][ni] = __builtin_amdgcn_mfma_f32_16x16x32_bf16(af[mi], bf, acc[mi][ni], 0, 0, 0); \
    } \
    __builtin_amdgcn_s_setprio(0); \
} while (0)

#define G2_STAGE(B, KB) do { \
    __builtin_amdgcn_global_load_lds((gas1_t)(pA0 + (KB)), (las3_t)(&As[B][dofs]), 16, 0, 0); \
    __builtin_amdgcn_global_load_lds((gas1_t)(pA1 + (KB)), (las3_t)(&As[B][2048 + dofs]), 16, 0, 0); \
    __builtin_amdgcn_global_load_lds((gas1_t)(pB0 + (KB)), (las3_t)(&Bs[B][dofs]), 16, 0, 0); \
    __builtin_amdgcn_global_load_lds((gas1_t)(pB1 + (KB)), (las3_t)(&Bs[B][2048 + dofs]), 16, 0, 0); \
} while (0)

__global__ __launch_bounds__(256, 4)
void k_gemm2s(const u16* __restrict__ act_g,  // [MAXROWS, I] bf16
              const u16* __restrict__ Wdt,    // [E,H,I] bf16
              const int* __restrict__ meta,
              float* __restrict__ y_g) {      // [MAXROWS, H] f32
    const int e = blockIdx.x;
    const int pcnt = meta[8 + e];
    const int m0 = blockIdx.z * 128;
    if (m0 >= pcnt) return;
    const int n0 = blockIdx.y * 128;
    const int off = meta[e];
    const int tid = threadIdx.x;
    const int wave = tid >> 6, lane = tid & 63;
    const int ln = lane & 15, q = lane >> 4;
    const int wr = (wave >> 1) * 64, wc = (wave & 1) * 64;

    __shared__ __align__(16) u16 As[2][128 * 32];
    __shared__ __align__(16) u16 Bs[2][128 * 32];

    // staging: 256 threads x 16B = half tile per issue; 2 issues per tile.
    const int srow = tid >> 2;                 // 0..63 (+64 for second half; swizzle identical)
    const int csw  = (((tid & 3) ^ ((srow >> 1) & 3))) * 8;
    const u16* bA = act_g + (size_t)(off + m0) * II;
    const u16* bB = Wdt + ((size_t)e * HH + n0) * II;
    const u16* pA0 = bA + (size_t)srow * II + csw;
    const u16* pA1 = bA + (size_t)(srow + 64) * II + csw;
    const u16* pB0 = bB + (size_t)srow * II + csw;
    const u16* pB1 = bB + (size_t)(srow + 64) * II + csw;
    const int dofs = tid * 8;

    const int qx = (q ^ ((ln >> 1) & 3)) * 8;

    f32x4 acc[4][4];
#pragma unroll
    for (int mi = 0; mi < 4; ++mi)
#pragma unroll
        for (int ni = 0; ni < 4; ++ni) acc[mi][ni] = (f32x4)0.f;

    // ---- 2-buffer counted-vmcnt pipeline over 44 K-tiles ----
    G2_STAGE(0, 0);
    int cur = 0;
    for (int t = 0; t < 43; ++t) {
        G2_STAGE(cur ^ 1, (t + 1) * 32);       // 8 outstanding / wave
        VM_WAIT(4);                            // tile t landed
        __builtin_amdgcn_s_barrier();
        G2_COMPUTE(cur);
        IR_FENCE();
        __builtin_amdgcn_s_barrier();
        cur ^= 1;
    }
    VM_WAIT(0);
    __builtin_amdgcn_s_barrier();
    G2_COMPUTE(cur);                           // tile 43

    // plain stores; padded rows (garbage) never read by k_combine
#pragma unroll
    for (int mi = 0; mi < 4; ++mi) {
#pragma unroll
        for (int r = 0; r < 4; ++r) {
            const int row = wr + mi * 16 + q * 4 + r;
            float* dst = y_g + (size_t)(off + m0 + row) * HH + n0 + wc;
#pragma unroll
            for (int ni = 0; ni < 4; ++ni)
                dst[ni * 16 + ln] = acc[mi][ni][r];
        }
    }
}

// ---------- combine: out[t] = y_g[slot0(t)] + y_g[slot1(t)] (weights folded in GEMM1) ----
__global__ void k_combine(const float* __restrict__ y_g, const int* __restrict__ slot,
                          const int* __restrict__ meta, const int* __restrict__ flag,
                          void* __restrict__ out) {
    const int gid = blockIdx.x * 256 + threadIdx.x;
    const int t = gid >> 9;                 // 512 threads per token row (H/4)
    const int h = (gid & 511) * 4;
    const int s0 = slot[t * 2 + 0], s1 = slot[t * 2 + 1];
    const int r0 = meta[s0 >> 11] + (s0 & 2047);   // TT == 2048
    const int r1 = meta[s1 >> 11] + (s1 & 2047);
    const float4 a = *(const float4*)&y_g[(size_t)r0 * HH + h];
    const float4 b = *(const float4*)&y_g[(size_t)r1 * HH + h];
    const float4 v = make_float4(a.x + b.x, a.y + b.y, a.z + b.z, a.w + b.w);
    if (flag[0]) {
        *(float4*)((float*)out + (size_t)t * HH + h) = v;
    } else {
        u16* o = (u16*)out + (size_t)t * HH + h;
        o[0] = f2bf(v.x); o[1] = f2bf(v.y); o[2] = f2bf(v.z); o[3] = f2bf(v.w);
    }
}

// ---------- launch ----------
extern "C" void kernel_launch(void* const* d_in, const int* in_sizes, int n_in,
                              void* d_out, int out_size, void* d_ws, size_t ws_size,
                              hipStream_t stream) {
    (void)in_sizes; (void)n_in; (void)out_size;
    const void* hs     = d_in[0];   // [T,H]
    const void* logits = d_in[1];   // [T,E]
    const void* Wg     = d_in[2];   // [E,H,I]
    const void* Wu     = d_in[3];   // [E,H,I]
    const void* Wd     = d_in[4];   // [E,I,H]

    char* ws = (char*)d_ws;
    size_t off = 0;
    int*   flag   = (int*)(ws + off);   off += 256;
    int*   counts = (int*)(ws + off);   off += 256;
    int*   meta   = (int*)(ws + off);   off += 256;
    int*   idx    = (int*)(ws + off);   off += (size_t)EE * TT * 4;       // 64 KB
    float* wt     = (float*)(ws + off); off += (size_t)EE * TT * 4;       // 64 KB
    int*   slot   = (int*)(ws + off);   off += (size_t)TT * 2 * 4;        // 16 KB
    u16*   hs_b   = (u16*)(ws + off);   off += (size_t)TT * HH * 2;       // 8 MB
    u16*   Wgt    = (u16*)(ws + off);   off += (size_t)EE * II * HH * 2;  // 46 MB [E,I,H]
    u16*   Wut    = (u16*)(ws + off);   off += (size_t)EE * II * HH * 2;  // 46 MB [E,I,H]
    u16*   Wdt    = (u16*)(ws + off);   off += (size_t)EE * HH * II * 2;  // 46 MB [E,H,I]
    u16*   act_g  = (u16*)(ws + off);   off += (size_t)MAXROWS * II * 2;  // 14.4 MB
    float* y_g    = (float*)(ws + off); off += (size_t)MAXROWS * HH * 4;  // 42 MB
    if (ws_size < off) return;

    k_sniff<<<dim3(1), dim3(256), 0, stream>>>((const u16*)hs, flag, counts);
    k_routing2<<<dim3(TT / 256), dim3(256), 0, stream>>>(logits, flag, counts, idx, wt, slot);
    k_offsets<<<dim3(1), dim3(64), 0, stream>>>(counts, meta);
    k_cast<<<dim3(TT * HH / (256 * 8)), dim3(256), 0, stream>>>(hs, flag, hs_b);
    // Wg [E,H,I] -> Wgt [E,I,H];  Wu likewise;  Wd [E,I,H] -> Wdt [E,H,I]
    k_transposeV<<<dim3(II / 64, HH / 64, EE), dim3(256), 0, stream>>>(Wg, flag, Wgt, HH, II);
    k_transposeV<<<dim3(II / 64, HH / 64, EE), dim3(256), 0, stream>>>(Wu, flag, Wut, HH, II);
    k_transposeV<<<dim3(HH / 64, II / 64, EE), dim3(256), 0, stream>>>(Wd, flag, Wdt, II, HH);
    // grid (e, n, m), m fastest: linear%8==e -> expert pinned to XCD; consecutive
    // blocks share the (e,n) B-panel in L2 (round-0 best mapping).
    k_gemm1s<<<dim3(EE, II / 128, TT / 128), dim3(512), 0, stream>>>(hs_b, Wgt, Wut, counts, meta, idx, wt, act_g);
    k_gemm2s<<<dim3(EE, HH / 128, TT / 128), dim3(256), 0, stream>>>(act_g, Wdt, meta, y_g);
    k_combine<<<dim3(TT * HH / (256 * 4)), dim3(256), 0, stream>>>(y_g, slot, meta, flag, d_out);
}